// Round 12
// baseline (245.603 us; speedup 1.0000x reference)
//
#include <hip/hip_runtime.h>
#include <hip/hip_bf16.h>
#include <math.h>

#define D_ 8
#define H_ 64
#define IN_ 17
#define SLOPE_ 0.2f
#define B_ 128
#define T_ 514
#define W_ 512
#define N_ (B_*W_)            // 65536
#define RES_SZ (N_*D_)        // 524288
#define LOG_OFF RES_SZ        // 524288
#define HJ_OFF (RES_SZ + B_)  // 524416

#define BSTR 72               // padded plane stride (64 = 32 banks -> conflicts)

// ws is all-ushort. Region 1: bwd planes (R12-verified layout), per d:
#define PERD_B 23040          // [w2tH][w2tL][w1tH][w1tL][w0tH][w0tL]
#define OB_W2H 0
#define OB_W2L 4608
#define OB_W1H 9216
#define OB_W1L 13824
#define OB_W0H 18432
#define OB_W0L 20736
// Region 2: fwd planes at ushort offset FWD_U, per d 27648 ushorts:
//   f0[h][k]=W0[h][k] (64x72, k<32 used, k>=17 zero)  f1[g][k]=W1[g][k]  f2[g][k]=W2[g][k]
#define FWD_U (D_*PERD_B)
#define PERD_F 27648
#define OF_W0H 0
#define OF_W0L 4608
#define OF_W1H 9216
#define OF_W1L 13824
#define OF_W2H 18432
#define OF_W2L 23040

typedef __attribute__((ext_vector_type(8))) short short8;
typedef __attribute__((ext_vector_type(4))) float float4v;

// HW RNE f32->bf16 (v_cvt path; m240: scalar cast beats hand-written asm).
__device__ __forceinline__ unsigned short f2bf(float x) {
    return __bfloat16_as_ushort(__float2bfloat16(x));
}
__device__ __forceinline__ float bf2f(unsigned short h) {
    return __uint_as_float(((unsigned)h) << 16);
}
// split2: hi = RNE(x), lo = RNE(x - hi).
__device__ __forceinline__ void split2(float x, short& hi, short& lo) {
    unsigned short h = f2bf(x);
    hi = (short)h;
    float r = x - bf2f(h);
    lo = (short)f2bf(r);
}

// R10-verified: 64 blocks (8 slices per d) — setup ~4us (was ~17 at 8 blocks).
__global__ void setup_kernel(const float* __restrict__ W0, const float* __restrict__ W1,
                             const float* __restrict__ W2,
                             unsigned short* __restrict__ ws, float* __restrict__ out) {
    int d = blockIdx.x >> 3;
    int s = blockIdx.x & 7;
    unsigned short* bb = ws + d * PERD_B;
    unsigned short* bf = ws + FWD_U + d * PERD_F;
    for (int idx = s * 512 + threadIdx.x; idx < (s + 1) * 512; idx += blockDim.x) {
        int r = idx >> 6, c = idx & 63;
        // bwd planes: w2t[n=r][k=c] = W2[k][n]
        float v2 = W2[d * H_ * H_ + c * H_ + r];
        unsigned short h2 = f2bf(v2);
        bb[OB_W2H + r * BSTR + c] = h2;
        bb[OB_W2L + r * BSTR + c] = f2bf(v2 - bf2f(h2));
        float v1 = W1[d * H_ * H_ + c * H_ + r];
        unsigned short h1 = f2bf(v1);
        bb[OB_W1H + r * BSTR + c] = h1;
        bb[OB_W1L + r * BSTR + c] = f2bf(v1 - bf2f(h1));
        // fwd planes: f1[g=r][k=c] = W1[r][c], f2 likewise
        float f1v = W1[(d * H_ + r) * H_ + c];
        unsigned short f1h = f2bf(f1v);
        bf[OF_W1H + r * BSTR + c] = f1h;
        bf[OF_W1L + r * BSTR + c] = f2bf(f1v - bf2f(f1h));
        float f2v = W2[(d * H_ + r) * H_ + c];
        unsigned short f2h = f2bf(f2v);
        bf[OF_W2H + r * BSTR + c] = f2h;
        bf[OF_W2L + r * BSTR + c] = f2bf(f2v - bf2f(f2h));
    }
    for (int idx = s * 256 + threadIdx.x; idx < (s + 1) * 256; idx += blockDim.x) {
        int nn = idx >> 6, k = idx & 63;               // bwd w0t[i=nn][j=k]
        float v = (nn < IN_) ? W0[(d * H_ + k) * IN_ + nn] : 0.0f;
        unsigned short h = f2bf(v);
        bb[OB_W0H + nn * BSTR + k] = h;
        bb[OB_W0L + nn * BSTR + k] = f2bf(v - bf2f(h));
        // fwd f0[h=k][kk=nn] = W0[k][nn] (nn>=17 zero)
        float fv = (nn < IN_) ? W0[(d * H_ + k) * IN_ + nn] : 0.0f;
        unsigned short fh = f2bf(fv);
        bf[OF_W0H + k * BSTR + nn] = fh;
        bf[OF_W0L + k * BSTR + nn] = f2bf(fv - bf2f(fh));
    }
    if (blockIdx.x == 0 && threadIdx.x < B_) out[LOG_OFF + threadIdx.x] = 0.0f;
}

// Fused fwd+bwd (R6-verified base: 124.4us — unroll x2 + logf-fold, NO setprio:
// R10 measured setprio at -4us, m190-like regression, reverted).
// This round: m0/m1 masks carried in per-lane u64 registers instead of
// ballot->LDS->reload. The bwd application at (row=q*4+r, col=nt*16+c) needs
// exactly the predicate this same lane computed at fwd epilogue iter (r,nt) —
// no cross-lane traffic. Bit = mti*16 + r*4 + nt (runtime-mti shift, no array
// indexing -> no scratch). Only m2 (bwd A-side, row-indexed by c) keeps the
// ballot+sM2 path. Deletes ~120 VALU/mti of ballot-packing in fwd and
// ~32 LDS scalar reads + addr calc per mti in bwd. Bitwise-identical outputs.
__global__ __launch_bounds__(256, 2) void fused_kernel(
    const float* __restrict__ x,
    const float* __restrict__ b0, const float* __restrict__ b1,
    const float* __restrict__ b2, const float* __restrict__ Wo,
    const float* __restrict__ bo, const unsigned short* __restrict__ ws,
    float* __restrict__ out)
{
    __shared__ __align__(16) unsigned short sB[PERD_F];   // 55.3 KB fwd planes
    __shared__ __align__(16) float sAct[4 * 16 * 68];     // 17.4 KB
    __shared__ unsigned sM2[256*2];                       // 2 KB (m2 only)
    __shared__ __align__(16) float sWo[H_];
    __shared__ float sRed[4];

    const int blk = blockIdx.x;
    const int d   = blk >> 8;
    const int t   = blk & 255;
    const int tid = threadIdx.x;
    const int n0  = t << 8;

    {
        const uint4* src = (const uint4*)(ws + FWD_U + d * PERD_F);
        uint4* dst = (uint4*)sB;
        for (int i = tid; i < PERD_F / 8; i += 256) dst[i] = src[i];
        if (tid < H_) sWo[tid] = Wo[d * H_ + tid];
    }

    const int wv   = tid >> 6;
    const int lane = tid & 63;
    const int q    = lane >> 4;
    const int c    = lane & 15;
    float* slot = sAct + wv * (16 * 68);

    // ---- bwd B-fragment prefetch: direct global gathers (16B aligned, L2-hot)
    const unsigned short* wb = ws + (size_t)d * PERD_B;
    short8 Bw2h[4][2], Bw2l[4][2], Bw1h[4][2], Bw1l[4][2], Bw0h[2][2], Bw0l[2][2];
#pragma unroll
    for (int nt = 0; nt < 4; ++nt)
#pragma unroll
        for (int kst = 0; kst < 2; ++kst) {
            int off = (nt*16 + c) * BSTR + (kst << 5) + (q << 3);
            Bw2h[nt][kst] = *(const short8*)(wb + OB_W2H + off);
            Bw2l[nt][kst] = *(const short8*)(wb + OB_W2L + off);
            Bw1h[nt][kst] = *(const short8*)(wb + OB_W1H + off);
            Bw1l[nt][kst] = *(const short8*)(wb + OB_W1L + off);
        }
#pragma unroll
    for (int nt = 0; nt < 2; ++nt)
#pragma unroll
        for (int kst = 0; kst < 2; ++kst) {
            int off = (nt*16 + c) * BSTR + (kst << 5) + (q << 3);
            Bw0h[nt][kst] = *(const short8*)(wb + OB_W0H + off);
            Bw0l[nt][kst] = *(const short8*)(wb + OB_W0L + off);
        }

    float b0v[4], b1v[4], b2v[4];
#pragma unroll
    for (int nt = 0; nt < 4; ++nt) {
        b0v[nt] = b0[d * H_ + nt * 16 + c];
        b1v[nt] = b1[d * H_ + nt * 16 + c];
        b2v[nt] = b2[d * H_ + nt * 16 + c];
    }
    const float bod = bo[d];

    // per-lane mask registers: bit (mti*16 + r*4 + nt)
    unsigned long long m0all = 0ull, m1all = 0ull;
    __syncthreads();

    // ================= forward phase =================
#pragma unroll 2
    for (int mti = 0; mti < 4; ++mti) {
        const int sbase = wv * 64 + mti * 16;
        const int gn    = n0 + sbase + c;        // this lane's A-row sample

        short8 ah[2], al[2];
        float4v acc[4];

        // ---- stage 0: A direct from x (K=32, kst=0 only)
        {
            const float* xp = x + (((gn >> 9) * T_) + (gn & 511)) * D_;
            float xs[8] = {0,0,0,0,0,0,0,0};
            if (q < 2) {
                float4 f0 = *(const float4*)(xp + q * 8);
                float4 f1 = *(const float4*)(xp + q * 8 + 4);
                xs[0]=f0.x; xs[1]=f0.y; xs[2]=f0.z; xs[3]=f0.w;
                xs[4]=f1.x; xs[5]=f1.y; xs[6]=f1.z; xs[7]=f1.w;
            } else if (q == 2) {
                xs[0] = xp[16 + d];
            }
#pragma unroll
            for (int j = 0; j < 8; ++j) { short h8,l8; split2(xs[j],h8,l8); ah[0][j]=h8; al[0][j]=l8; }
        }
#pragma unroll
        for (int nt = 0; nt < 4; ++nt) {
            int off = (nt*16 + c) * BSTR + (q << 3);
            short8 bh = *(const short8*)(sB + OF_W0H + off);
            short8 bl = *(const short8*)(sB + OF_W0L + off);
            float4v a = {0.f,0.f,0.f,0.f};
            a = __builtin_amdgcn_mfma_f32_16x16x32_bf16(ah[0], bh, a, 0,0,0);
            a = __builtin_amdgcn_mfma_f32_16x16x32_bf16(al[0], bh, a, 0,0,0);
            a = __builtin_amdgcn_mfma_f32_16x16x32_bf16(ah[0], bl, a, 0,0,0);
            acc[nt] = a;
        }
        // epilogue 0: bias + leaky -> slot; predicates -> m0all register
#pragma unroll
        for (int r = 0; r < 4; ++r) {
#pragma unroll
            for (int nt = 0; nt < 4; ++nt) {
                float hv = acc[nt][r] + b0v[nt];
                bool p = hv > 0.0f;
                m0all |= ((unsigned long long)(p ? 1u : 0u)) << (mti*16 + r*4 + nt);
                slot[(q*4+r)*68 + nt*16 + c] = p ? hv : hv * SLOPE_;
            }
        }

        // ---- stage 1: A from slot, B = W1 planes (K=64)
#pragma unroll
        for (int kst = 0; kst < 2; ++kst) {
            const float* p = slot + c * 68 + kst * 32 + q * 8;
            float4 f0 = *(const float4*)p, f1 = *(const float4*)(p + 4);
            float xs[8] = {f0.x,f0.y,f0.z,f0.w,f1.x,f1.y,f1.z,f1.w};
#pragma unroll
            for (int j = 0; j < 8; ++j) { short h8,l8; split2(xs[j],h8,l8); ah[kst][j]=h8; al[kst][j]=l8; }
        }
#pragma unroll
        for (int nt = 0; nt < 4; ++nt) {
            float4v a = {0.f,0.f,0.f,0.f};
#pragma unroll
            for (int kst = 0; kst < 2; ++kst) {
                int off = (nt*16 + c) * BSTR + (kst << 5) + (q << 3);
                short8 bh = *(const short8*)(sB + OF_W1H + off);
                short8 bl = *(const short8*)(sB + OF_W1L + off);
                a = __builtin_amdgcn_mfma_f32_16x16x32_bf16(ah[kst], bh, a, 0,0,0);
                a = __builtin_amdgcn_mfma_f32_16x16x32_bf16(al[kst], bh, a, 0,0,0);
                a = __builtin_amdgcn_mfma_f32_16x16x32_bf16(ah[kst], bl, a, 0,0,0);
            }
            acc[nt] = a;
        }
        // epilogue 1: predicates -> m1all register
#pragma unroll
        for (int r = 0; r < 4; ++r) {
#pragma unroll
            for (int nt = 0; nt < 4; ++nt) {
                float hv = acc[nt][r] + b1v[nt];
                bool p = hv > 0.0f;
                m1all |= ((unsigned long long)(p ? 1u : 0u)) << (mti*16 + r*4 + nt);
                slot[(q*4+r)*68 + nt*16 + c] = p ? hv : hv * SLOPE_;
            }
        }

        // ---- stage 2: A from slot, B = W2 planes (K=64)
#pragma unroll
        for (int kst = 0; kst < 2; ++kst) {
            const float* p = slot + c * 68 + kst * 32 + q * 8;
            float4 f0 = *(const float4*)p, f1 = *(const float4*)(p + 4);
            float xs[8] = {f0.x,f0.y,f0.z,f0.w,f1.x,f1.y,f1.z,f1.w};
#pragma unroll
            for (int j = 0; j < 8; ++j) { short h8,l8; split2(xs[j],h8,l8); ah[kst][j]=h8; al[kst][j]=l8; }
        }
#pragma unroll
        for (int nt = 0; nt < 4; ++nt) {
            float4v a = {0.f,0.f,0.f,0.f};
#pragma unroll
            for (int kst = 0; kst < 2; ++kst) {
                int off = (nt*16 + c) * BSTR + (kst << 5) + (q << 3);
                short8 bh = *(const short8*)(sB + OF_W2H + off);
                short8 bl = *(const short8*)(sB + OF_W2L + off);
                a = __builtin_amdgcn_mfma_f32_16x16x32_bf16(ah[kst], bh, a, 0,0,0);
                a = __builtin_amdgcn_mfma_f32_16x16x32_bf16(al[kst], bh, a, 0,0,0);
                a = __builtin_amdgcn_mfma_f32_16x16x32_bf16(ah[kst], bl, a, 0,0,0);
            }
            acc[nt] = a;
        }
        // epilogue 2: m2 needs the cross-lane (row-indexed) transpose -> ballot+LDS
#pragma unroll
        for (int r = 0; r < 4; ++r) {
            float hv[4]; bool p[4];
#pragma unroll
            for (int nt = 0; nt < 4; ++nt) { hv[nt] = acc[nt][r] + b2v[nt]; p[nt] = hv[nt] > 0.0f; }
            unsigned long long B0 = __ballot(p[0]), B1 = __ballot(p[1]);
            unsigned long long B2 = __ballot(p[2]), B3 = __ballot(p[3]);
            if (c == 0) {
                int row = sbase + q * 4 + r;
                sM2[row*2]   = (unsigned)((B0 >> (q*16)) & 0xffffull) | ((unsigned)((B1 >> (q*16)) & 0xffffull) << 16);
                sM2[row*2+1] = (unsigned)((B2 >> (q*16)) & 0xffffull) | ((unsigned)((B3 >> (q*16)) & 0xffffull) << 16);
            }
#pragma unroll
            for (int nt = 0; nt < 4; ++nt)
                slot[(q*4+r)*68 + nt*16 + c] = p[nt] ? hv[nt] : hv[nt] * SLOPE_;
        }

        // ---- residual: row c, partial over this lane's 16-col segment, shfl over q
        {
            const float* srow = slot + c * 68 + q * 16;
            const float* wop  = sWo + q * 16;
            float4 s0 = *(const float4*)srow,       s1 = *(const float4*)(srow + 4);
            float4 s2 = *(const float4*)(srow + 8), s3 = *(const float4*)(srow + 12);
            float4 w0 = *(const float4*)wop,        w1 = *(const float4*)(wop + 4);
            float4 w2 = *(const float4*)(wop + 8),  w3 = *(const float4*)(wop + 12);
            float part = s0.x*w0.x + s0.y*w0.y + s0.z*w0.z + s0.w*w0.w
                       + s1.x*w1.x + s1.y*w1.y + s1.z*w1.z + s1.w*w1.w
                       + s2.x*w2.x + s2.y*w2.y + s2.z*w2.z + s2.w*w2.w
                       + s3.x*w3.x + s3.y*w3.y + s3.z*w3.z + s3.w*w3.w;
            part += __shfl_xor(part, 16, 64);
            part += __shfl_xor(part, 32, 64);
            if (q == 0) out[gn * D_ + d] = part + bod;
        }
    }

    // ================= backward phase =================
    // No barrier needed: sM2 rows consumed below are produced by this same wave
    // above; m0all/m1all are lane-private registers; sB is read-only.
    float ld = 0.0f;

#pragma unroll 2
    for (int mti = 0; mti < 4; ++mti) {
        const int sbase = wv * 64 + mti * 16;

        short8 ah[2];
        float4v acc[4];

#pragma unroll
        for (int kst = 0; kst < 2; ++kst) {
            unsigned mm = sM2[(sbase + c) * 2 + kst];
            const float* wop = sWo + kst * 32 + q * 8;
            float4 e0 = *(const float4*)wop, e1 = *(const float4*)(wop + 4);
            float xs[8] = {e0.x,e0.y,e0.z,e0.w,e1.x,e1.y,e1.z,e1.w};
#pragma unroll
            for (int j = 0; j < 8; ++j) {
                int kk = q * 8 + j;
                float v = xs[j] * (((mm >> kk) & 1u) ? 1.0f : SLOPE_);
                ah[kst][j] = (short)f2bf(v);
            }
        }
#pragma unroll
        for (int nt = 0; nt < 4; ++nt) {
            float4v a = {0.f,0.f,0.f,0.f};
#pragma unroll
            for (int kst = 0; kst < 2; ++kst) {
                a = __builtin_amdgcn_mfma_f32_16x16x32_bf16(ah[kst], Bw2h[nt][kst], a, 0,0,0);
                a = __builtin_amdgcn_mfma_f32_16x16x32_bf16(ah[kst], Bw2l[nt][kst], a, 0,0,0);
            }
            acc[nt] = a;
        }
        // apply m1 from this lane's own register (same (r,nt) bits as fwd)
#pragma unroll
        for (int nt = 0; nt < 4; ++nt)
#pragma unroll
            for (int r = 0; r < 4; ++r) {
                unsigned bit = (unsigned)((m1all >> (mti*16 + r*4 + nt)) & 1ull);
                float v = acc[nt][r];
                slot[(q*4+r) * 68 + nt*16 + c] = bit ? v : v * SLOPE_;
            }

#pragma unroll
        for (int kst = 0; kst < 2; ++kst) {
            const float* p = slot + c * 68 + kst * 32 + q * 8;
            float4 f0 = *(const float4*)p, f1 = *(const float4*)(p + 4);
            float xs[8] = {f0.x,f0.y,f0.z,f0.w,f1.x,f1.y,f1.z,f1.w};
#pragma unroll
            for (int j = 0; j < 8; ++j) ah[kst][j] = (short)f2bf(xs[j]);
        }
#pragma unroll
        for (int nt = 0; nt < 4; ++nt) {
            float4v a = {0.f,0.f,0.f,0.f};
#pragma unroll
            for (int kst = 0; kst < 2; ++kst) {
                a = __builtin_amdgcn_mfma_f32_16x16x32_bf16(ah[kst], Bw1h[nt][kst], a, 0,0,0);
                a = __builtin_amdgcn_mfma_f32_16x16x32_bf16(ah[kst], Bw1l[nt][kst], a, 0,0,0);
            }
            acc[nt] = a;
        }
        // apply m0 from register
#pragma unroll
        for (int nt = 0; nt < 4; ++nt)
#pragma unroll
            for (int r = 0; r < 4; ++r) {
                unsigned bit = (unsigned)((m0all >> (mti*16 + r*4 + nt)) & 1ull);
                float v = acc[nt][r];
                slot[(q*4+r) * 68 + nt*16 + c] = bit ? v : v * SLOPE_;
            }

#pragma unroll
        for (int kst = 0; kst < 2; ++kst) {
            const float* p = slot + c * 68 + kst * 32 + q * 8;
            float4 f0 = *(const float4*)p, f1 = *(const float4*)(p + 4);
            float xs[8] = {f0.x,f0.y,f0.z,f0.w,f1.x,f1.y,f1.z,f1.w};
#pragma unroll
            for (int j = 0; j < 8; ++j) ah[kst][j] = (short)f2bf(xs[j]);
        }
#pragma unroll
        for (int nt = 0; nt < 2; ++nt) {
            float4v a = {0.f,0.f,0.f,0.f};
#pragma unroll
            for (int kst = 0; kst < 2; ++kst) {
                a = __builtin_amdgcn_mfma_f32_16x16x32_bf16(ah[kst], Bw0h[nt][kst], a, 0,0,0);
                a = __builtin_amdgcn_mfma_f32_16x16x32_bf16(ah[kst], Bw0l[nt][kst], a, 0,0,0);
            }
            acc[nt] = a;
        }
#pragma unroll
        for (int r = 0; r < 4; ++r) {
            int gn = n0 + sbase + q * 4 + r;
            out[HJ_OFF + ((size_t)d * N_ + gn) * 16 + c] = acc[0][r];
        }
        if (c == 0) {
            // one logf of the 4-way product instead of 4 logf (range-safe)
            float pr = acc[1][0] * acc[1][1] * acc[1][2] * acc[1][3];
            ld += logf(fabsf(pr));
        }
    }

#pragma unroll
    for (int off = 32; off > 0; off >>= 1)
        ld += __shfl_down(ld, off, 64);
    if (lane == 0) sRed[wv] = ld;
    __syncthreads();
    if (tid == 0)
        atomicAdd(out + LOG_OFF + (t >> 1), (sRed[0] + sRed[1]) + (sRed[2] + sRed[3]));
}

extern "C" void kernel_launch(void* const* d_in, const int* in_sizes, int n_in,
                              void* d_out, int out_size, void* d_ws, size_t ws_size,
                              hipStream_t stream) {
    const float* x  = (const float*)d_in[0];
    const float* W0 = (const float*)d_in[1];
    const float* b0 = (const float*)d_in[2];
    const float* W1 = (const float*)d_in[3];
    const float* b1 = (const float*)d_in[4];
    const float* W2 = (const float*)d_in[5];
    const float* b2 = (const float*)d_in[6];
    const float* Wo = (const float*)d_in[7];
    const float* bo = (const float*)d_in[8];
    float* out = (float*)d_out;
    unsigned short* ws = (unsigned short*)d_ws;   // 368KB bwd + 442KB fwd planes

    hipLaunchKernelGGL(setup_kernel, dim3(D_ * 8), dim3(256), 0, stream, W0, W1, W2, ws, out);
    hipLaunchKernelGGL(fused_kernel, dim3(D_ * 256), dim3(256), 0, stream,
                       x, b0, b1, b2, Wo, bo, ws, out);
}

// Round 13
// 188.390 us; speedup vs baseline: 1.3037x; 1.3037x over previous
//
#include <hip/hip_runtime.h>
#include <hip/hip_bf16.h>
#include <math.h>

#define D_ 8
#define H_ 64
#define IN_ 17
#define SLOPE_ 0.2f
#define B_ 128
#define T_ 514
#define W_ 512
#define N_ (B_*W_)            // 65536
#define RES_SZ (N_*D_)        // 524288
#define LOG_OFF RES_SZ        // 524288
#define HJ_OFF (RES_SZ + B_)  // 524416

#define BSTR 72               // padded plane stride (64 = 32 banks -> conflicts)

// ws is all-ushort. Region 1: bwd planes (R12-verified layout), per d:
#define PERD_B 23040          // [w2tH][w2tL][w1tH][w1tL][w0tH][w0tL]
#define OB_W2H 0
#define OB_W2L 4608
#define OB_W1H 9216
#define OB_W1L 13824
#define OB_W0H 18432
#define OB_W0L 20736
// Region 2: fwd planes at ushort offset FWD_U, per d 27648 ushorts:
//   f0[h][k]=W0[h][k] (64x72, k<32 used, k>=17 zero)  f1[g][k]=W1[g][k]  f2[g][k]=W2[g][k]
#define FWD_U (D_*PERD_B)
#define PERD_F 27648
#define OF_W0H 0
#define OF_W0L 4608
#define OF_W1H 9216
#define OF_W1L 13824
#define OF_W2H 18432
#define OF_W2L 23040

typedef __attribute__((ext_vector_type(8))) short short8;
typedef __attribute__((ext_vector_type(4))) float float4v;

// HW RNE f32->bf16 (v_cvt path; m240: scalar cast beats hand-written asm).
__device__ __forceinline__ unsigned short f2bf(float x) {
    return __bfloat16_as_ushort(__float2bfloat16(x));
}
__device__ __forceinline__ float bf2f(unsigned short h) {
    return __uint_as_float(((unsigned)h) << 16);
}
// split2: hi = RNE(x), lo = RNE(x - hi).
__device__ __forceinline__ void split2(float x, short& hi, short& lo) {
    unsigned short h = f2bf(x);
    hi = (short)h;
    float r = x - bf2f(h);
    lo = (short)f2bf(r);
}

// R10-verified: 64 blocks (8 slices per d) — setup ~4us (was ~17 at 8 blocks).
__global__ void setup_kernel(const float* __restrict__ W0, const float* __restrict__ W1,
                             const float* __restrict__ W2,
                             unsigned short* __restrict__ ws, float* __restrict__ out) {
    int d = blockIdx.x >> 3;
    int s = blockIdx.x & 7;
    unsigned short* bb = ws + d * PERD_B;
    unsigned short* bf = ws + FWD_U + d * PERD_F;
    for (int idx = s * 512 + threadIdx.x; idx < (s + 1) * 512; idx += blockDim.x) {
        int r = idx >> 6, c = idx & 63;
        // bwd planes: w2t[n=r][k=c] = W2[k][n]
        float v2 = W2[d * H_ * H_ + c * H_ + r];
        unsigned short h2 = f2bf(v2);
        bb[OB_W2H + r * BSTR + c] = h2;
        bb[OB_W2L + r * BSTR + c] = f2bf(v2 - bf2f(h2));
        float v1 = W1[d * H_ * H_ + c * H_ + r];
        unsigned short h1 = f2bf(v1);
        bb[OB_W1H + r * BSTR + c] = h1;
        bb[OB_W1L + r * BSTR + c] = f2bf(v1 - bf2f(h1));
        // fwd planes: f1[g=r][k=c] = W1[r][c], f2 likewise
        float f1v = W1[(d * H_ + r) * H_ + c];
        unsigned short f1h = f2bf(f1v);
        bf[OF_W1H + r * BSTR + c] = f1h;
        bf[OF_W1L + r * BSTR + c] = f2bf(f1v - bf2f(f1h));
        float f2v = W2[(d * H_ + r) * H_ + c];
        unsigned short f2h = f2bf(f2v);
        bf[OF_W2H + r * BSTR + c] = f2h;
        bf[OF_W2L + r * BSTR + c] = f2bf(f2v - bf2f(f2h));
    }
    for (int idx = s * 256 + threadIdx.x; idx < (s + 1) * 256; idx += blockDim.x) {
        int nn = idx >> 6, k = idx & 63;               // bwd w0t[i=nn][j=k]
        float v = (nn < IN_) ? W0[(d * H_ + k) * IN_ + nn] : 0.0f;
        unsigned short h = f2bf(v);
        bb[OB_W0H + nn * BSTR + k] = h;
        bb[OB_W0L + nn * BSTR + k] = f2bf(v - bf2f(h));
        // fwd f0[h=k][kk=nn] = W0[k][nn] (nn>=17 zero)
        float fv = (nn < IN_) ? W0[(d * H_ + k) * IN_ + nn] : 0.0f;
        unsigned short fh = f2bf(fv);
        bf[OF_W0H + k * BSTR + nn] = fh;
        bf[OF_W0L + k * BSTR + nn] = f2bf(fv - bf2f(fh));
    }
    if (blockIdx.x == 0 && threadIdx.x < B_) out[LOG_OFF + threadIdx.x] = 0.0f;
}

// Fused fwd+bwd — EXACT R6-verified body (124.4us): unroll x2 + logf-fold,
// ballot->LDS masks for all three levels, no setprio. R12 post-mortem:
// register-carried u64 masks (runtime-shift accumulate) went to scratch
// (+224MB HBM spill traffic, fused 180us) — REVERTED. setprio was a
// measured -4us (R10) — stays out.
__global__ __launch_bounds__(256, 2) void fused_kernel(
    const float* __restrict__ x,
    const float* __restrict__ b0, const float* __restrict__ b1,
    const float* __restrict__ b2, const float* __restrict__ Wo,
    const float* __restrict__ bo, const unsigned short* __restrict__ ws,
    float* __restrict__ out)
{
    __shared__ __align__(16) unsigned short sB[PERD_F];   // 55.3 KB fwd planes
    __shared__ __align__(16) float sAct[4 * 16 * 68];     // 17.4 KB
    __shared__ unsigned sM0[256*2], sM1[256*2], sM2[256*2];
    __shared__ __align__(16) float sWo[H_];
    __shared__ float sRed[4];

    const int blk = blockIdx.x;
    const int d   = blk >> 8;
    const int t   = blk & 255;
    const int tid = threadIdx.x;
    const int n0  = t << 8;

    {
        const uint4* src = (const uint4*)(ws + FWD_U + d * PERD_F);
        uint4* dst = (uint4*)sB;
        for (int i = tid; i < PERD_F / 8; i += 256) dst[i] = src[i];
        if (tid < H_) sWo[tid] = Wo[d * H_ + tid];
    }

    const int wv   = tid >> 6;
    const int lane = tid & 63;
    const int q    = lane >> 4;
    const int c    = lane & 15;
    float* slot = sAct + wv * (16 * 68);

    // ---- bwd B-fragment prefetch: direct global gathers (16B aligned, L2-hot)
    const unsigned short* wb = ws + (size_t)d * PERD_B;
    short8 Bw2h[4][2], Bw2l[4][2], Bw1h[4][2], Bw1l[4][2], Bw0h[2][2], Bw0l[2][2];
#pragma unroll
    for (int nt = 0; nt < 4; ++nt)
#pragma unroll
        for (int kst = 0; kst < 2; ++kst) {
            int off = (nt*16 + c) * BSTR + (kst << 5) + (q << 3);
            Bw2h[nt][kst] = *(const short8*)(wb + OB_W2H + off);
            Bw2l[nt][kst] = *(const short8*)(wb + OB_W2L + off);
            Bw1h[nt][kst] = *(const short8*)(wb + OB_W1H + off);
            Bw1l[nt][kst] = *(const short8*)(wb + OB_W1L + off);
        }
#pragma unroll
    for (int nt = 0; nt < 2; ++nt)
#pragma unroll
        for (int kst = 0; kst < 2; ++kst) {
            int off = (nt*16 + c) * BSTR + (kst << 5) + (q << 3);
            Bw0h[nt][kst] = *(const short8*)(wb + OB_W0H + off);
            Bw0l[nt][kst] = *(const short8*)(wb + OB_W0L + off);
        }

    float b0v[4], b1v[4], b2v[4];
#pragma unroll
    for (int nt = 0; nt < 4; ++nt) {
        b0v[nt] = b0[d * H_ + nt * 16 + c];
        b1v[nt] = b1[d * H_ + nt * 16 + c];
        b2v[nt] = b2[d * H_ + nt * 16 + c];
    }
    const float bod = bo[d];
    __syncthreads();

    // ================= forward phase =================
#pragma unroll 2
    for (int mti = 0; mti < 4; ++mti) {
        const int sbase = wv * 64 + mti * 16;
        const int gn    = n0 + sbase + c;        // this lane's A-row sample

        short8 ah[2], al[2];
        float4v acc[4];

        // ---- stage 0: A direct from x (K=32, kst=0 only)
        {
            const float* xp = x + (((gn >> 9) * T_) + (gn & 511)) * D_;
            float xs[8] = {0,0,0,0,0,0,0,0};
            if (q < 2) {
                float4 f0 = *(const float4*)(xp + q * 8);
                float4 f1 = *(const float4*)(xp + q * 8 + 4);
                xs[0]=f0.x; xs[1]=f0.y; xs[2]=f0.z; xs[3]=f0.w;
                xs[4]=f1.x; xs[5]=f1.y; xs[6]=f1.z; xs[7]=f1.w;
            } else if (q == 2) {
                xs[0] = xp[16 + d];
            }
#pragma unroll
            for (int j = 0; j < 8; ++j) { short h8,l8; split2(xs[j],h8,l8); ah[0][j]=h8; al[0][j]=l8; }
        }
#pragma unroll
        for (int nt = 0; nt < 4; ++nt) {
            int off = (nt*16 + c) * BSTR + (q << 3);
            short8 bh = *(const short8*)(sB + OF_W0H + off);
            short8 bl = *(const short8*)(sB + OF_W0L + off);
            float4v a = {0.f,0.f,0.f,0.f};
            a = __builtin_amdgcn_mfma_f32_16x16x32_bf16(ah[0], bh, a, 0,0,0);
            a = __builtin_amdgcn_mfma_f32_16x16x32_bf16(al[0], bh, a, 0,0,0);
            a = __builtin_amdgcn_mfma_f32_16x16x32_bf16(ah[0], bl, a, 0,0,0);
            acc[nt] = a;
        }
        // epilogue 0: bias + ballot masks -> sM0 + leaky -> slot
#pragma unroll
        for (int r = 0; r < 4; ++r) {
            float hv[4]; bool p[4];
#pragma unroll
            for (int nt = 0; nt < 4; ++nt) { hv[nt] = acc[nt][r] + b0v[nt]; p[nt] = hv[nt] > 0.0f; }
            unsigned long long B0 = __ballot(p[0]), B1 = __ballot(p[1]);
            unsigned long long B2 = __ballot(p[2]), B3 = __ballot(p[3]);
            if (c == 0) {
                int row = sbase + q * 4 + r;
                sM0[row*2]   = (unsigned)((B0 >> (q*16)) & 0xffffull) | ((unsigned)((B1 >> (q*16)) & 0xffffull) << 16);
                sM0[row*2+1] = (unsigned)((B2 >> (q*16)) & 0xffffull) | ((unsigned)((B3 >> (q*16)) & 0xffffull) << 16);
            }
#pragma unroll
            for (int nt = 0; nt < 4; ++nt)
                slot[(q*4+r)*68 + nt*16 + c] = p[nt] ? hv[nt] : hv[nt] * SLOPE_;
        }

        // ---- stage 1: A from slot, B = W1 planes (K=64)
#pragma unroll
        for (int kst = 0; kst < 2; ++kst) {
            const float* p = slot + c * 68 + kst * 32 + q * 8;
            float4 f0 = *(const float4*)p, f1 = *(const float4*)(p + 4);
            float xs[8] = {f0.x,f0.y,f0.z,f0.w,f1.x,f1.y,f1.z,f1.w};
#pragma unroll
            for (int j = 0; j < 8; ++j) { short h8,l8; split2(xs[j],h8,l8); ah[kst][j]=h8; al[kst][j]=l8; }
        }
#pragma unroll
        for (int nt = 0; nt < 4; ++nt) {
            float4v a = {0.f,0.f,0.f,0.f};
#pragma unroll
            for (int kst = 0; kst < 2; ++kst) {
                int off = (nt*16 + c) * BSTR + (kst << 5) + (q << 3);
                short8 bh = *(const short8*)(sB + OF_W1H + off);
                short8 bl = *(const short8*)(sB + OF_W1L + off);
                a = __builtin_amdgcn_mfma_f32_16x16x32_bf16(ah[kst], bh, a, 0,0,0);
                a = __builtin_amdgcn_mfma_f32_16x16x32_bf16(al[kst], bh, a, 0,0,0);
                a = __builtin_amdgcn_mfma_f32_16x16x32_bf16(ah[kst], bl, a, 0,0,0);
            }
            acc[nt] = a;
        }
#pragma unroll
        for (int r = 0; r < 4; ++r) {
            float hv[4]; bool p[4];
#pragma unroll
            for (int nt = 0; nt < 4; ++nt) { hv[nt] = acc[nt][r] + b1v[nt]; p[nt] = hv[nt] > 0.0f; }
            unsigned long long B0 = __ballot(p[0]), B1 = __ballot(p[1]);
            unsigned long long B2 = __ballot(p[2]), B3 = __ballot(p[3]);
            if (c == 0) {
                int row = sbase + q * 4 + r;
                sM1[row*2]   = (unsigned)((B0 >> (q*16)) & 0xffffull) | ((unsigned)((B1 >> (q*16)) & 0xffffull) << 16);
                sM1[row*2+1] = (unsigned)((B2 >> (q*16)) & 0xffffull) | ((unsigned)((B3 >> (q*16)) & 0xffffull) << 16);
            }
#pragma unroll
            for (int nt = 0; nt < 4; ++nt)
                slot[(q*4+r)*68 + nt*16 + c] = p[nt] ? hv[nt] : hv[nt] * SLOPE_;
        }

        // ---- stage 2: A from slot, B = W2 planes (K=64)
#pragma unroll
        for (int kst = 0; kst < 2; ++kst) {
            const float* p = slot + c * 68 + kst * 32 + q * 8;
            float4 f0 = *(const float4*)p, f1 = *(const float4*)(p + 4);
            float xs[8] = {f0.x,f0.y,f0.z,f0.w,f1.x,f1.y,f1.z,f1.w};
#pragma unroll
            for (int j = 0; j < 8; ++j) { short h8,l8; split2(xs[j],h8,l8); ah[kst][j]=h8; al[kst][j]=l8; }
        }
#pragma unroll
        for (int nt = 0; nt < 4; ++nt) {
            float4v a = {0.f,0.f,0.f,0.f};
#pragma unroll
            for (int kst = 0; kst < 2; ++kst) {
                int off = (nt*16 + c) * BSTR + (kst << 5) + (q << 3);
                short8 bh = *(const short8*)(sB + OF_W2H + off);
                short8 bl = *(const short8*)(sB + OF_W2L + off);
                a = __builtin_amdgcn_mfma_f32_16x16x32_bf16(ah[kst], bh, a, 0,0,0);
                a = __builtin_amdgcn_mfma_f32_16x16x32_bf16(al[kst], bh, a, 0,0,0);
                a = __builtin_amdgcn_mfma_f32_16x16x32_bf16(ah[kst], bl, a, 0,0,0);
            }
            acc[nt] = a;
        }
#pragma unroll
        for (int r = 0; r < 4; ++r) {
            float hv[4]; bool p[4];
#pragma unroll
            for (int nt = 0; nt < 4; ++nt) { hv[nt] = acc[nt][r] + b2v[nt]; p[nt] = hv[nt] > 0.0f; }
            unsigned long long B0 = __ballot(p[0]), B1 = __ballot(p[1]);
            unsigned long long B2 = __ballot(p[2]), B3 = __ballot(p[3]);
            if (c == 0) {
                int row = sbase + q * 4 + r;
                sM2[row*2]   = (unsigned)((B0 >> (q*16)) & 0xffffull) | ((unsigned)((B1 >> (q*16)) & 0xffffull) << 16);
                sM2[row*2+1] = (unsigned)((B2 >> (q*16)) & 0xffffull) | ((unsigned)((B3 >> (q*16)) & 0xffffull) << 16);
            }
#pragma unroll
            for (int nt = 0; nt < 4; ++nt)
                slot[(q*4+r)*68 + nt*16 + c] = p[nt] ? hv[nt] : hv[nt] * SLOPE_;
        }

        // ---- residual: row c, partial over this lane's 16-col segment, shfl over q
        {
            const float* srow = slot + c * 68 + q * 16;
            const float* wop  = sWo + q * 16;
            float4 s0 = *(const float4*)srow,       s1 = *(const float4*)(srow + 4);
            float4 s2 = *(const float4*)(srow + 8), s3 = *(const float4*)(srow + 12);
            float4 w0 = *(const float4*)wop,        w1 = *(const float4*)(wop + 4);
            float4 w2 = *(const float4*)(wop + 8),  w3 = *(const float4*)(wop + 12);
            float part = s0.x*w0.x + s0.y*w0.y + s0.z*w0.z + s0.w*w0.w
                       + s1.x*w1.x + s1.y*w1.y + s1.z*w1.z + s1.w*w1.w
                       + s2.x*w2.x + s2.y*w2.y + s2.z*w2.z + s2.w*w2.w
                       + s3.x*w3.x + s3.y*w3.y + s3.z*w3.z + s3.w*w3.w;
            part += __shfl_xor(part, 16, 64);
            part += __shfl_xor(part, 32, 64);
            if (q == 0) out[gn * D_ + d] = part + bod;
        }
    }

    // ================= backward phase =================
    // No barrier needed: sM rows consumed below are produced by this same wave
    // above; sB is read-only throughout. Waves desync -> natural phase overlap.
    float ld = 0.0f;

#pragma unroll 2
    for (int mti = 0; mti < 4; ++mti) {
        const int sbase = wv * 64 + mti * 16;

        short8 ah[2];
        float4v acc[4];

#pragma unroll
        for (int kst = 0; kst < 2; ++kst) {
            unsigned mm = sM2[(sbase + c) * 2 + kst];
            const float* wop = sWo + kst * 32 + q * 8;
            float4 e0 = *(const float4*)wop, e1 = *(const float4*)(wop + 4);
            float xs[8] = {e0.x,e0.y,e0.z,e0.w,e1.x,e1.y,e1.z,e1.w};
#pragma unroll
            for (int j = 0; j < 8; ++j) {
                int kk = q * 8 + j;
                float v = xs[j] * (((mm >> kk) & 1u) ? 1.0f : SLOPE_);
                ah[kst][j] = (short)f2bf(v);
            }
        }
#pragma unroll
        for (int nt = 0; nt < 4; ++nt) {
            float4v a = {0.f,0.f,0.f,0.f};
#pragma unroll
            for (int kst = 0; kst < 2; ++kst) {
                a = __builtin_amdgcn_mfma_f32_16x16x32_bf16(ah[kst], Bw2h[nt][kst], a, 0,0,0);
                a = __builtin_amdgcn_mfma_f32_16x16x32_bf16(ah[kst], Bw2l[nt][kst], a, 0,0,0);
            }
            acc[nt] = a;
        }
#pragma unroll
        for (int nt = 0; nt < 4; ++nt)
#pragma unroll
            for (int r = 0; r < 4; ++r) {
                int row = q * 4 + r, col = nt * 16 + c;
                unsigned bit = (sM1[(sbase + row) * 2 + (col >> 5)] >> (col & 31)) & 1u;
                float v = acc[nt][r];
                slot[row * 68 + col] = bit ? v : v * SLOPE_;
            }

#pragma unroll
        for (int kst = 0; kst < 2; ++kst) {
            const float* p = slot + c * 68 + kst * 32 + q * 8;
            float4 f0 = *(const float4*)p, f1 = *(const float4*)(p + 4);
            float xs[8] = {f0.x,f0.y,f0.z,f0.w,f1.x,f1.y,f1.z,f1.w};
#pragma unroll
            for (int j = 0; j < 8; ++j) ah[kst][j] = (short)f2bf(xs[j]);
        }
#pragma unroll
        for (int nt = 0; nt < 4; ++nt) {
            float4v a = {0.f,0.f,0.f,0.f};
#pragma unroll
            for (int kst = 0; kst < 2; ++kst) {
                a = __builtin_amdgcn_mfma_f32_16x16x32_bf16(ah[kst], Bw1h[nt][kst], a, 0,0,0);
                a = __builtin_amdgcn_mfma_f32_16x16x32_bf16(ah[kst], Bw1l[nt][kst], a, 0,0,0);
            }
            acc[nt] = a;
        }
#pragma unroll
        for (int nt = 0; nt < 4; ++nt)
#pragma unroll
            for (int r = 0; r < 4; ++r) {
                int row = q * 4 + r, col = nt * 16 + c;
                unsigned bit = (sM0[(sbase + row) * 2 + (col >> 5)] >> (col & 31)) & 1u;
                float v = acc[nt][r];
                slot[row * 68 + col] = bit ? v : v * SLOPE_;
            }

#pragma unroll
        for (int kst = 0; kst < 2; ++kst) {
            const float* p = slot + c * 68 + kst * 32 + q * 8;
            float4 f0 = *(const float4*)p, f1 = *(const float4*)(p + 4);
            float xs[8] = {f0.x,f0.y,f0.z,f0.w,f1.x,f1.y,f1.z,f1.w};
#pragma unroll
            for (int j = 0; j < 8; ++j) ah[kst][j] = (short)f2bf(xs[j]);
        }
#pragma unroll
        for (int nt = 0; nt < 2; ++nt) {
            float4v a = {0.f,0.f,0.f,0.f};
#pragma unroll
            for (int kst = 0; kst < 2; ++kst) {
                a = __builtin_amdgcn_mfma_f32_16x16x32_bf16(ah[kst], Bw0h[nt][kst], a, 0,0,0);
                a = __builtin_amdgcn_mfma_f32_16x16x32_bf16(ah[kst], Bw0l[nt][kst], a, 0,0,0);
            }
            acc[nt] = a;
        }
#pragma unroll
        for (int r = 0; r < 4; ++r) {
            int gn = n0 + sbase + q * 4 + r;
            out[HJ_OFF + ((size_t)d * N_ + gn) * 16 + c] = acc[0][r];
        }
        if (c == 0) {
            // one logf of the 4-way product instead of 4 logf (range-safe;
            // shortens the divergent transcendental tail on the c==0 lanes)
            float pr = acc[1][0] * acc[1][1] * acc[1][2] * acc[1][3];
            ld += logf(fabsf(pr));
        }
    }

#pragma unroll
    for (int off = 32; off > 0; off >>= 1)
        ld += __shfl_down(ld, off, 64);
    if (lane == 0) sRed[wv] = ld;
    __syncthreads();
    if (tid == 0)
        atomicAdd(out + LOG_OFF + (t >> 1), (sRed[0] + sRed[1]) + (sRed[2] + sRed[3]));
}

extern "C" void kernel_launch(void* const* d_in, const int* in_sizes, int n_in,
                              void* d_out, int out_size, void* d_ws, size_t ws_size,
                              hipStream_t stream) {
    const float* x  = (const float*)d_in[0];
    const float* W0 = (const float*)d_in[1];
    const float* b0 = (const float*)d_in[2];
    const float* W1 = (const float*)d_in[3];
    const float* b1 = (const float*)d_in[4];
    const float* W2 = (const float*)d_in[5];
    const float* b2 = (const float*)d_in[6];
    const float* Wo = (const float*)d_in[7];
    const float* bo = (const float*)d_in[8];
    float* out = (float*)d_out;
    unsigned short* ws = (unsigned short*)d_ws;   // 368KB bwd + 442KB fwd planes

    hipLaunchKernelGGL(setup_kernel, dim3(D_ * 8), dim3(256), 0, stream, W0, W1, W2, ws, out);
    hipLaunchKernelGGL(fused_kernel, dim3(D_ * 256), dim3(256), 0, stream,
                       x, b0, b1, b2, Wo, bo, ws, out);
}